// Round 6
// baseline (349.777 us; speedup 1.0000x reference)
//
#include <hip/hip_runtime.h>
#include <hip/hip_bf16.h>

#define NN 100000
#define NE 1600000
#define BK2 391             // row buckets: row >> 8, rows 0..99999 -> 0..390
#define CAP2 4864           // slots per bucket (mean 4096, sigma ~64, +12 sigma)
#define CHUNK2 4096         // edges per phase-A workgroup (391 blocks)

typedef _Float16 f16;
typedef f16 f16x8 __attribute__((ext_vector_type(8)));
typedef float f32x4 __attribute__((ext_vector_type(4)));

// ---------------- prep: zero bcursor + transpose W1,W2 to f16 n-major ----------------
// grid: 96 blocks x 256 = 24576 threads (16384 for Wt1, 8192 for Wt2)
__global__ __launch_bounds__(256) void prep(const float* __restrict__ W1,
                                            const float* __restrict__ W2,
                                            f16* __restrict__ Wt1,
                                            f16* __restrict__ Wt2,
                                            int* __restrict__ bcursor) {
    int gid = blockIdx.x * 256 + threadIdx.x;
    if (gid < BK2) bcursor[gid] = 0;
    if (gid < 16384) {                       // Wt1[n*128+k] = W1[k*128+n]
        int n = gid >> 7, k = gid & 127;
        Wt1[gid] = (f16)W1[k * 128 + n];
    } else if (gid < 24576) {                // Wt2[n*128+k] = W2[k*64+n]
        int e = gid - 16384;
        int n = e >> 7, k = e & 127;
        Wt2[e] = (f16)W2[k * 64 + n];
    }
}

// ---------------- adjacency build: two-phase binned CSR (391-way) ----------------

__global__ __launch_bounds__(256) void bin_edges(const int* __restrict__ row,
                                                 const int* __restrict__ col,
                                                 int* __restrict__ bcursor,
                                                 int2* __restrict__ binned) {
    __shared__ int  bcnt[BK2];
    __shared__ int  bbase[BK2];
    __shared__ int  lstart[BK2];
    __shared__ int  bcur[BK2];
    __shared__ int  sca[BK2];
    __shared__ int  scb[BK2];
    __shared__ int2 stage[CHUNK2];
    int tid = threadIdx.x;
    int e0 = blockIdx.x * CHUNK2;
    int emax = min(CHUNK2, NE - e0);

    for (int i = tid; i < BK2; i += 256) bcnt[i] = 0;
    __syncthreads();
    for (int i = tid; i < emax; i += 256)
        atomicAdd(&bcnt[row[e0 + i] >> 8], 1);
    __syncthreads();

    // parallel inclusive scan of bcnt (ping-pong, 9 rounds)
    for (int i = tid; i < BK2; i += 256) sca[i] = bcnt[i];
    __syncthreads();
    int* pa = sca; int* pb = scb;
    for (int s = 1; s < BK2; s <<= 1) {
        for (int i = tid; i < BK2; i += 256)
            pb[i] = pa[i] + ((i >= s) ? pa[i - s] : 0);
        __syncthreads();
        int* t = pa; pa = pb; pb = t;
    }
    for (int i = tid; i < BK2; i += 256) {
        int ex = pa[i] - bcnt[i];              // exclusive
        lstart[i] = ex;
        bcur[i]   = ex;
        bbase[i]  = atomicAdd(&bcursor[i], bcnt[i]);   // run start within bucket
    }
    __syncthreads();

    for (int i = tid; i < emax; i += 256) {
        int r = row[e0 + i], c = col[e0 + i];
        int pos = atomicAdd(&bcur[r >> 8], 1);
        stage[pos] = make_int2(r, c);
    }
    __syncthreads();
    for (int i = tid; i < emax; i += 256) {
        int2 rc = stage[i];
        int b = rc.x >> 8;
        binned[(size_t)b * CAP2 + bbase[b] + (i - lstart[b])] = rc;
    }
}

__global__ __launch_bounds__(256) void build_csr(const int* __restrict__ bcount,
                                                 const int2* __restrict__ binned,
                                                 int* __restrict__ offsets,
                                                 float* __restrict__ dinv,
                                                 int* __restrict__ csr_col) {
    __shared__ int cnt[256];
    __shared__ int sc[256];
    __shared__ int red[256];
    __shared__ int colbuf[CAP2];
    int tid = threadIdx.x;
    int b = blockIdx.x;
    int r0 = b << 8;
    int nrows = min(256, NN - r0);

    // global base = sum bcount[0..b-1], parallel reduce
    int part = 0;
    for (int i = tid; i < b; i += 256) part += bcount[i];
    red[tid] = part;
    cnt[tid] = 0;
    __syncthreads();
    #pragma unroll
    for (int s = 128; s > 0; s >>= 1) {
        if (tid < s) red[tid] += red[tid + s];
        __syncthreads();
    }
    int mybase = red[0];
    int n = bcount[b];
    const int2* src = binned + (size_t)b * CAP2;

    for (int i = tid; i < n; i += 256)
        atomicAdd(&cnt[src[i].x - r0], 1);
    __syncthreads();

    // inclusive scan of cnt -> sc (8 rounds)
    int v = cnt[tid];
    sc[tid] = v;
    __syncthreads();
    #pragma unroll
    for (int s = 1; s < 256; s <<= 1) {
        int t = (tid >= s) ? sc[tid - s] : 0;
        __syncthreads();
        sc[tid] += t;
        __syncthreads();
    }
    int incl = sc[tid];
    if (tid < nrows) {
        offsets[r0 + tid + 1] = mybase + incl;
        dinv[r0 + tid] = rsqrtf((float)(v + 1));   // +1 self loop
    }
    if (b == 0 && tid == 0) offsets[0] = 0;

    cnt[tid] = incl - v;   // exclusive -> local cursor
    __syncthreads();
    for (int i = tid; i < n; i += 256) {
        int2 rc = src[i];
        int pos = atomicAdd(&cnt[rc.x - r0], 1);
        colbuf[pos] = rc.y;
    }
    __syncthreads();
    for (int i = tid; i < n; i += 256)
        csr_col[mybase + i] = colbuf[i];
}

// ---------------- MFMA f16 GEMM (layer 1 only, fp32 A): 128 rows/block ----------------
// 4 waves; each wave owns 32 rows as TWO 16-row m-tiles sharing the same Wt
// fragment reads. Halves per-block W-staging traffic vs the 64-row version.
__global__ __launch_bounds__(256) void gemm_mfma128(const float* __restrict__ Af,
                                                    const float* __restrict__ W,
                                                    const float* __restrict__ dinv,
                                                    f16* __restrict__ T) {
    constexpr int F = 128;
    constexpr int PITCH = 136;
    __shared__ f16 Wt[F * PITCH];
    int tid = threadIdx.x;
    for (int e = tid; e < 128 * F; e += 256) {
        int k = e / F, n = e - k * F;
        Wt[n * PITCH + k] = (f16)W[e];
    }
    __syncthreads();

    int wave = tid >> 6;
    int lane = tid & 63;
    int m = lane & 15, q = lane >> 4;
    int r0 = blockIdx.x * 128 + wave * 32;     // wave covers rows r0..r0+31
    int raA = min(r0 + m, NN - 1);
    int raB = min(r0 + 16 + m, NN - 1);

    constexpr int NT = F / 16;
    f32x4 accA[NT], accB[NT];
    #pragma unroll
    for (int t = 0; t < NT; ++t) { accA[t] = (f32x4){0.f,0.f,0.f,0.f}; accB[t] = (f32x4){0.f,0.f,0.f,0.f}; }

    #pragma unroll
    for (int c = 0; c < 4; ++c) {              // K = 128 = 4 x 32
        f16x8 aA, aB;
        {
            const float4* p = (const float4*)&Af[(size_t)raA * 128 + c * 32 + q * 8];
            float4 lo = p[0], hi = p[1];
            aA[0]=(f16)lo.x; aA[1]=(f16)lo.y; aA[2]=(f16)lo.z; aA[3]=(f16)lo.w;
            aA[4]=(f16)hi.x; aA[5]=(f16)hi.y; aA[6]=(f16)hi.z; aA[7]=(f16)hi.w;
        }
        {
            const float4* p = (const float4*)&Af[(size_t)raB * 128 + c * 32 + q * 8];
            float4 lo = p[0], hi = p[1];
            aB[0]=(f16)lo.x; aB[1]=(f16)lo.y; aB[2]=(f16)lo.z; aB[3]=(f16)lo.w;
            aB[4]=(f16)hi.x; aB[5]=(f16)hi.y; aB[6]=(f16)hi.z; aB[7]=(f16)hi.w;
        }
        #pragma unroll
        for (int t = 0; t < NT; ++t) {
            f16x8 b = *(const f16x8*)&Wt[(t * 16 + m) * PITCH + c * 32 + q * 8];
            accA[t] = __builtin_amdgcn_mfma_f32_16x16x32_f16(aA, b, accA[t], 0, 0, 0);
            accB[t] = __builtin_amdgcn_mfma_f32_16x16x32_f16(aB, b, accB[t], 0, 0, 0);
        }
    }

    #pragma unroll
    for (int half = 0; half < 2; ++half) {
        f32x4* acc = half ? accB : accA;
        int rbase = r0 + half * 16;
        #pragma unroll
        for (int i = 0; i < 4; ++i) {
            int rr = rbase + q * 4 + i;
            if (rr < NN) {
                float dv = dinv[rr];
                #pragma unroll
                for (int t = 0; t < NT; ++t)
                    T[(size_t)rr * F + t * 16 + m] = (f16)(acc[t][i] * dv);
            }
        }
    }
}

// ---------------- FUSED: SpMM gather + next-layer GEMM (W from global) ----------------
// 256 threads = 16 rows x 16 lanes; (256,8) -> 8 blocks/CU, VGPR budget 64.
// For F2=64 the 4 B-fragments are preloaded into registers before the gather
// (+16 VGPR, ~48 total) so the MFMA phase has no global dependency.
// Grid must be exactly NN/16 blocks.
template<int F2>
__global__ __launch_bounds__(256, 8) void spmm_gemm(const f16* __restrict__ T,
                                                    const int* __restrict__ offsets,
                                                    const int* __restrict__ csr_col,
                                                    const float* __restrict__ dinv,
                                                    const float* __restrict__ bias,
                                                    const f16* __restrict__ WtG,
                                                    f16* __restrict__ Tout) {
    constexpr int PITCH = 136;                 // f16 units; 272 B rows, 16B-aligned
    __shared__ f16 hbuf[16 * PITCH];           // 16 rows of h (and out-bounce)
    int tid = threadIdx.x;

    constexpr int FW  = F2 / 4;                 // feats per wave: 32 (F2=128) or 16
    constexpr int NTW = FW / 16;                // tiles per wave: 2 or 1
    int wv = tid >> 6, wl = tid & 63;
    int wm = wl & 15, wq = wl >> 4;
    int fg = wv;                                // 0..3

    f16x8 bpre[4];
    if constexpr (NTW == 1) {                   // F2=64: preload all B-fragments
        #pragma unroll
        for (int c = 0; c < 4; ++c)
            bpre[c] = *(const f16x8*)&WtG[((size_t)(fg * FW + wm)) * 128 + c * 32 + wq * 8];
    }

    // ---- gather phase ----
    int lane = tid & 15;                       // 16 lanes per row, 16 B each
    int rs   = tid >> 4;                       // 0..15
    int r    = blockIdx.x * 16 + rs;

    const f16x8* Tv = (const f16x8*)T;
    int o0 = offsets[r], o1 = offsets[r + 1];

    float s[8];
    f16x8 self = Tv[(size_t)r * 16 + lane];
    #pragma unroll
    for (int u = 0; u < 8; ++u) s[u] = (float)self[u];

    int j = o0;
    for (; j + 8 <= o1; j += 8) {
        int c0 = csr_col[j],     c1 = csr_col[j + 1], c2 = csr_col[j + 2], c3 = csr_col[j + 3];
        int c4 = csr_col[j + 4], c5 = csr_col[j + 5], c6 = csr_col[j + 6], c7 = csr_col[j + 7];
        f16x8 v0 = Tv[(size_t)c0 * 16 + lane];
        f16x8 v1 = Tv[(size_t)c1 * 16 + lane];
        f16x8 v2 = Tv[(size_t)c2 * 16 + lane];
        f16x8 v3 = Tv[(size_t)c3 * 16 + lane];
        f16x8 v4 = Tv[(size_t)c4 * 16 + lane];
        f16x8 v5 = Tv[(size_t)c5 * 16 + lane];
        f16x8 v6 = Tv[(size_t)c6 * 16 + lane];
        f16x8 v7 = Tv[(size_t)c7 * 16 + lane];
        #pragma unroll
        for (int u = 0; u < 8; ++u) {
            s[u] += ((float)v0[u] + (float)v1[u]) + ((float)v2[u] + (float)v3[u])
                  + ((float)v4[u] + (float)v5[u]) + ((float)v6[u] + (float)v7[u]);
        }
    }
    for (; j + 4 <= o1; j += 4) {
        int c0 = csr_col[j], c1 = csr_col[j + 1], c2 = csr_col[j + 2], c3 = csr_col[j + 3];
        f16x8 v0 = Tv[(size_t)c0 * 16 + lane];
        f16x8 v1 = Tv[(size_t)c1 * 16 + lane];
        f16x8 v2 = Tv[(size_t)c2 * 16 + lane];
        f16x8 v3 = Tv[(size_t)c3 * 16 + lane];
        #pragma unroll
        for (int u = 0; u < 8; ++u)
            s[u] += ((float)v0[u] + (float)v1[u]) + ((float)v2[u] + (float)v3[u]);
    }
    for (; j < o1; ++j) {
        int c = csr_col[j];
        f16x8 v = Tv[(size_t)c * 16 + lane];
        #pragma unroll
        for (int u = 0; u < 8; ++u) s[u] += (float)v[u];
    }

    float dr = dinv[r];
    f16x8 h;
    #pragma unroll
    for (int u = 0; u < 8; ++u) {
        float o = fmaf(dr, s[u], bias[lane * 8 + u]);
        h[u] = (f16)fmaxf(o, 0.f);             // both fused layers have relu
    }
    *(f16x8*)&hbuf[rs * PITCH + lane * 8] = h;
    __syncthreads();                            // h complete

    // ---- MFMA phase: 4 waves; wave fg owns feature group fg of all 16 rows ----
    f32x4 acc[NTW];
    #pragma unroll
    for (int t = 0; t < NTW; ++t) acc[t] = (f32x4){0.f, 0.f, 0.f, 0.f};

    #pragma unroll
    for (int c = 0; c < 4; ++c) {
        f16x8 a = *(const f16x8*)&hbuf[wm * PITCH + c * 32 + wq * 8];
        if constexpr (NTW == 1) {
            acc[0] = __builtin_amdgcn_mfma_f32_16x16x32_f16(a, bpre[c], acc[0], 0, 0, 0);
        } else {
            #pragma unroll
            for (int t = 0; t < NTW; ++t) {
                f16x8 b = *(const f16x8*)&WtG[((size_t)(fg * FW + t * 16 + wm)) * 128 + c * 32 + wq * 8];
                acc[t] = __builtin_amdgcn_mfma_f32_16x16x32_f16(a, b, acc[t], 0, 0, 0);
            }
        }
    }
    __syncthreads();                            // all A-reads done before hbuf reuse

    // ---- dinv scale + LDS bounce for coalesced f16 writeout ----
    #pragma unroll
    for (int i = 0; i < 4; ++i) {
        int rloc = wq * 4 + i;
        float dv = dinv[blockIdx.x * 16 + rloc];
        #pragma unroll
        for (int t = 0; t < NTW; ++t)
            hbuf[rloc * PITCH + fg * FW + t * 16 + wm] = (f16)(acc[t][i] * dv);
    }
    __syncthreads();

    constexpr int LPO = F2 / 8;                 // f16x8 per row
    for (int e = tid; e < 16 * LPO; e += 256) {
        int rr = e / LPO, ff = e - rr * LPO;
        ((f16x8*)Tout)[(size_t)(blockIdx.x * 16 + rr) * LPO + ff] =
            *(f16x8*)&hbuf[rr * PITCH + ff * 8];
    }
}

// ---------------- SpMM gather on f16 T (final layer) ----------------
template<int F, bool RELU, bool OUTF16>
__global__ __launch_bounds__(256, 8) void spmm_h(const f16* __restrict__ T,
                                                 const int* __restrict__ offsets,
                                                 const int* __restrict__ csr_col,
                                                 const float* __restrict__ dinv,
                                                 const float* __restrict__ bias,
                                                 void* __restrict__ outv) {
    constexpr int LPR = F / 8;
    constexpr int RPB = 256 / LPR;
    int lane = threadIdx.x % LPR;
    int rs   = threadIdx.x / LPR;
    int r    = blockIdx.x * RPB + rs;
    if (r >= NN) return;

    const f16x8* Tv = (const f16x8*)T;
    int o0 = offsets[r], o1 = offsets[r + 1];

    float s[8];
    f16x8 self = Tv[(size_t)r * LPR + lane];
    #pragma unroll
    for (int u = 0; u < 8; ++u) s[u] = (float)self[u];

    int j = o0;
    for (; j + 8 <= o1; j += 8) {
        int c0 = csr_col[j],     c1 = csr_col[j + 1], c2 = csr_col[j + 2], c3 = csr_col[j + 3];
        int c4 = csr_col[j + 4], c5 = csr_col[j + 5], c6 = csr_col[j + 6], c7 = csr_col[j + 7];
        f16x8 v0 = Tv[(size_t)c0 * LPR + lane];
        f16x8 v1 = Tv[(size_t)c1 * LPR + lane];
        f16x8 v2 = Tv[(size_t)c2 * LPR + lane];
        f16x8 v3 = Tv[(size_t)c3 * LPR + lane];
        f16x8 v4 = Tv[(size_t)c4 * LPR + lane];
        f16x8 v5 = Tv[(size_t)c5 * LPR + lane];
        f16x8 v6 = Tv[(size_t)c6 * LPR + lane];
        f16x8 v7 = Tv[(size_t)c7 * LPR + lane];
        #pragma unroll
        for (int u = 0; u < 8; ++u) {
            s[u] += ((float)v0[u] + (float)v1[u]) + ((float)v2[u] + (float)v3[u])
                  + ((float)v4[u] + (float)v5[u]) + ((float)v6[u] + (float)v7[u]);
        }
    }
    for (; j + 4 <= o1; j += 4) {
        int c0 = csr_col[j], c1 = csr_col[j + 1], c2 = csr_col[j + 2], c3 = csr_col[j + 3];
        f16x8 v0 = Tv[(size_t)c0 * LPR + lane];
        f16x8 v1 = Tv[(size_t)c1 * LPR + lane];
        f16x8 v2 = Tv[(size_t)c2 * LPR + lane];
        f16x8 v3 = Tv[(size_t)c3 * LPR + lane];
        #pragma unroll
        for (int u = 0; u < 8; ++u)
            s[u] += ((float)v0[u] + (float)v1[u]) + ((float)v2[u] + (float)v3[u]);
    }
    for (; j < o1; ++j) {
        int c = csr_col[j];
        f16x8 v = Tv[(size_t)c * LPR + lane];
        #pragma unroll
        for (int u = 0; u < 8; ++u) s[u] += (float)v[u];
    }

    float dr = dinv[r];
    float o[8];
    #pragma unroll
    for (int u = 0; u < 8; ++u) {
        o[u] = fmaf(dr, s[u], bias[lane * 8 + u]);
        if (RELU) o[u] = fmaxf(o[u], 0.f);
    }

    if (OUTF16) {
        f16x8 h;
        #pragma unroll
        for (int u = 0; u < 8; ++u) h[u] = (f16)o[u];
        ((f16x8*)outv)[(size_t)r * LPR + lane] = h;
    } else {
        float* outF = (float*)outv;
        float4 lo = make_float4(o[0], o[1], o[2], o[3]);
        float4 hi = make_float4(o[4], o[5], o[6], o[7]);
        *(float4*)&outF[(size_t)r * F + lane * 8]     = lo;
        *(float4*)&outF[(size_t)r * F + lane * 8 + 4] = hi;
    }
}

// ---------------- launch ----------------

extern "C" void kernel_launch(void* const* d_in, const int* in_sizes, int n_in,
                              void* d_out, int out_size, void* d_ws, size_t ws_size,
                              hipStream_t stream) {
    const float* x  = (const float*)d_in[0];
    const int*   ei = (const int*)d_in[1];
    const float* W0 = (const float*)d_in[2];
    const float* b0 = (const float*)d_in[3];
    const float* W1 = (const float*)d_in[4];
    const float* b1 = (const float*)d_in[5];
    const float* W2 = (const float*)d_in[6];
    const float* b2 = (const float*)d_in[7];
    float* out = (float*)d_out;

    const int* row = ei;
    const int* col = ei + NE;

    char* wsp = (char*)d_ws;
    auto alloc = [&](size_t bytes) {
        char* p = wsp;
        wsp += (bytes + 255) & ~(size_t)255;
        return p;
    };
    int*   bcursor = (int*)alloc((size_t)BK2 * 4);          // run cursor, ends as bucket count
    int2*  binned  = (int2*)alloc((size_t)BK2 * CAP2 * 8);  // 15.2 MB
    int*   offsets = (int*)alloc((size_t)(NN + 1) * 4);
    float* dinv    = (float*)alloc((size_t)NN * 4);
    int*   csr_col = (int*)alloc((size_t)NE * 4);
    f16*   Tbuf    = (f16*)alloc((size_t)NN * 128 * 2);
    f16*   Hbuf    = (f16*)alloc((size_t)NN * 128 * 2);
    f16*   Wt1     = (f16*)alloc((size_t)128 * 128 * 2);    // W1 transposed f16
    f16*   Wt2     = (f16*)alloc((size_t)64 * 128 * 2);     // W2 transposed f16

    // prep (zero bcursor + W transposes) + adjacency build
    prep<<<96, 256, 0, stream>>>(W1, W2, Wt1, Wt2, bcursor);
    bin_edges<<<(NE + CHUNK2 - 1) / CHUNK2, 256, 0, stream>>>(row, col, bcursor, binned);
    build_csr<<<BK2, 256, 0, stream>>>(bcursor, binned, offsets, dinv, csr_col);

    const int GB128 = (NN + 127) / 128;  // 782
    const int FB16  = NN / 16;           // 6250, exact (NN % 16 == 0)

    // layer 1 GEMM (fp32 x): T1 = f16(dinv * (x @ W0))
    gemm_mfma128<<<GB128, 256, 0, stream>>>(x, W0, dinv, Tbuf);
    // fused: H1 = relu(spmm(T1) + b0);  T2 = f16(dinv * (H1 @ W1))
    spmm_gemm<128><<<FB16, 256, 0, stream>>>(Tbuf, offsets, csr_col, dinv, b0, Wt1, Hbuf);
    // fused: H2 = relu(spmm(T2) + b1);  T3 = f16(dinv * (H2 @ W2))
    spmm_gemm<64><<<FB16, 256, 0, stream>>>(Hbuf, offsets, csr_col, dinv, b1, Wt2, Tbuf);
    // final: out = spmm(T3) + b2   (fp32, no relu)
    spmm_h<64, false, false><<<(NN + 31) / 32, 256, 0, stream>>>(Tbuf, offsets, csr_col, dinv, b2, out);
}

// Round 7
// 321.375 us; speedup vs baseline: 1.0884x; 1.0884x over previous
//
#include <hip/hip_runtime.h>
#include <hip/hip_bf16.h>

#define NN 100000
#define NE 1600000
#define BK2 391             // row buckets: row >> 8, rows 0..99999 -> 0..390
#define CAP2 4864           // slots per bucket (mean 4096, sigma ~64, +12 sigma)
#define CHUNK2 4096         // edges per phase-A workgroup (391 blocks)

typedef _Float16 f16;
typedef f16 f16x8 __attribute__((ext_vector_type(8)));
typedef float f32x4 __attribute__((ext_vector_type(4)));

// ---------------- prep: zero bcursor + transpose W1,W2 to f16 n-major ----------------
// grid: 96 blocks x 256 = 24576 threads (16384 for Wt1, 8192 for Wt2)
__global__ __launch_bounds__(256) void prep(const float* __restrict__ W1,
                                            const float* __restrict__ W2,
                                            f16* __restrict__ Wt1,
                                            f16* __restrict__ Wt2,
                                            int* __restrict__ bcursor) {
    int gid = blockIdx.x * 256 + threadIdx.x;
    if (gid < BK2) bcursor[gid] = 0;
    if (gid < 16384) {                       // Wt1[n*128+k] = W1[k*128+n]
        int n = gid >> 7, k = gid & 127;
        Wt1[gid] = (f16)W1[k * 128 + n];
    } else if (gid < 24576) {                // Wt2[n*128+k] = W2[k*64+n]
        int e = gid - 16384;
        int n = e >> 7, k = e & 127;
        Wt2[e] = (f16)W2[k * 64 + n];
    }
}

// ---------------- adjacency build: two-phase binned CSR (391-way) ----------------

__global__ __launch_bounds__(256) void bin_edges(const int* __restrict__ row,
                                                 const int* __restrict__ col,
                                                 int* __restrict__ bcursor,
                                                 int2* __restrict__ binned) {
    __shared__ int  bcnt[BK2];
    __shared__ int  bbase[BK2];
    __shared__ int  lstart[BK2];
    __shared__ int  bcur[BK2];
    __shared__ int  sca[BK2];
    __shared__ int  scb[BK2];
    __shared__ int2 stage[CHUNK2];
    int tid = threadIdx.x;
    int e0 = blockIdx.x * CHUNK2;
    int emax = min(CHUNK2, NE - e0);

    for (int i = tid; i < BK2; i += 256) bcnt[i] = 0;
    __syncthreads();
    for (int i = tid; i < emax; i += 256)
        atomicAdd(&bcnt[row[e0 + i] >> 8], 1);
    __syncthreads();

    // parallel inclusive scan of bcnt (ping-pong, 9 rounds)
    for (int i = tid; i < BK2; i += 256) sca[i] = bcnt[i];
    __syncthreads();
    int* pa = sca; int* pb = scb;
    for (int s = 1; s < BK2; s <<= 1) {
        for (int i = tid; i < BK2; i += 256)
            pb[i] = pa[i] + ((i >= s) ? pa[i - s] : 0);
        __syncthreads();
        int* t = pa; pa = pb; pb = t;
    }
    for (int i = tid; i < BK2; i += 256) {
        int ex = pa[i] - bcnt[i];              // exclusive
        lstart[i] = ex;
        bcur[i]   = ex;
        bbase[i]  = atomicAdd(&bcursor[i], bcnt[i]);   // run start within bucket
    }
    __syncthreads();

    for (int i = tid; i < emax; i += 256) {
        int r = row[e0 + i], c = col[e0 + i];
        int pos = atomicAdd(&bcur[r >> 8], 1);
        stage[pos] = make_int2(r, c);
    }
    __syncthreads();
    for (int i = tid; i < emax; i += 256) {
        int2 rc = stage[i];
        int b = rc.x >> 8;
        binned[(size_t)b * CAP2 + bbase[b] + (i - lstart[b])] = rc;
    }
}

__global__ __launch_bounds__(256) void build_csr(const int* __restrict__ bcount,
                                                 const int2* __restrict__ binned,
                                                 int* __restrict__ offsets,
                                                 float* __restrict__ dinv,
                                                 int* __restrict__ csr_col) {
    __shared__ int cnt[256];
    __shared__ int sc[256];
    __shared__ int red[256];
    __shared__ int colbuf[CAP2];
    int tid = threadIdx.x;
    int b = blockIdx.x;
    int r0 = b << 8;
    int nrows = min(256, NN - r0);

    // global base = sum bcount[0..b-1], parallel reduce
    int part = 0;
    for (int i = tid; i < b; i += 256) part += bcount[i];
    red[tid] = part;
    cnt[tid] = 0;
    __syncthreads();
    #pragma unroll
    for (int s = 128; s > 0; s >>= 1) {
        if (tid < s) red[tid] += red[tid + s];
        __syncthreads();
    }
    int mybase = red[0];
    int n = bcount[b];
    const int2* src = binned + (size_t)b * CAP2;

    for (int i = tid; i < n; i += 256)
        atomicAdd(&cnt[src[i].x - r0], 1);
    __syncthreads();

    // inclusive scan of cnt -> sc (8 rounds)
    int v = cnt[tid];
    sc[tid] = v;
    __syncthreads();
    #pragma unroll
    for (int s = 1; s < 256; s <<= 1) {
        int t = (tid >= s) ? sc[tid - s] : 0;
        __syncthreads();
        sc[tid] += t;
        __syncthreads();
    }
    int incl = sc[tid];
    if (tid < nrows) {
        offsets[r0 + tid + 1] = mybase + incl;
        dinv[r0 + tid] = rsqrtf((float)(v + 1));   // +1 self loop
    }
    if (b == 0 && tid == 0) offsets[0] = 0;

    cnt[tid] = incl - v;   // exclusive -> local cursor
    __syncthreads();
    for (int i = tid; i < n; i += 256) {
        int2 rc = src[i];
        int pos = atomicAdd(&cnt[rc.x - r0], 1);
        colbuf[pos] = rc.y;
    }
    __syncthreads();
    for (int i = tid; i < n; i += 256)
        csr_col[mybase + i] = colbuf[i];
}

// ---------------- MFMA f16 GEMM (layer 1 only, fp32 A): 128 rows/block ----------------
// 4 waves; each wave owns 32 rows as TWO 16-row m-tiles sharing the same Wt
// fragment reads. Halves per-block W-staging traffic vs the 64-row version.
__global__ __launch_bounds__(256) void gemm_mfma128(const float* __restrict__ Af,
                                                    const float* __restrict__ W,
                                                    const float* __restrict__ dinv,
                                                    f16* __restrict__ T) {
    constexpr int F = 128;
    constexpr int PITCH = 136;
    __shared__ f16 Wt[F * PITCH];
    int tid = threadIdx.x;
    for (int e = tid; e < 128 * F; e += 256) {
        int k = e / F, n = e - k * F;
        Wt[n * PITCH + k] = (f16)W[e];
    }
    __syncthreads();

    int wave = tid >> 6;
    int lane = tid & 63;
    int m = lane & 15, q = lane >> 4;
    int r0 = blockIdx.x * 128 + wave * 32;     // wave covers rows r0..r0+31
    int raA = min(r0 + m, NN - 1);
    int raB = min(r0 + 16 + m, NN - 1);

    constexpr int NT = F / 16;
    f32x4 accA[NT], accB[NT];
    #pragma unroll
    for (int t = 0; t < NT; ++t) { accA[t] = (f32x4){0.f,0.f,0.f,0.f}; accB[t] = (f32x4){0.f,0.f,0.f,0.f}; }

    #pragma unroll
    for (int c = 0; c < 4; ++c) {              // K = 128 = 4 x 32
        f16x8 aA, aB;
        {
            const float4* p = (const float4*)&Af[(size_t)raA * 128 + c * 32 + q * 8];
            float4 lo = p[0], hi = p[1];
            aA[0]=(f16)lo.x; aA[1]=(f16)lo.y; aA[2]=(f16)lo.z; aA[3]=(f16)lo.w;
            aA[4]=(f16)hi.x; aA[5]=(f16)hi.y; aA[6]=(f16)hi.z; aA[7]=(f16)hi.w;
        }
        {
            const float4* p = (const float4*)&Af[(size_t)raB * 128 + c * 32 + q * 8];
            float4 lo = p[0], hi = p[1];
            aB[0]=(f16)lo.x; aB[1]=(f16)lo.y; aB[2]=(f16)lo.z; aB[3]=(f16)lo.w;
            aB[4]=(f16)hi.x; aB[5]=(f16)hi.y; aB[6]=(f16)hi.z; aB[7]=(f16)hi.w;
        }
        #pragma unroll
        for (int t = 0; t < NT; ++t) {
            f16x8 b = *(const f16x8*)&Wt[(t * 16 + m) * PITCH + c * 32 + q * 8];
            accA[t] = __builtin_amdgcn_mfma_f32_16x16x32_f16(aA, b, accA[t], 0, 0, 0);
            accB[t] = __builtin_amdgcn_mfma_f32_16x16x32_f16(aB, b, accB[t], 0, 0, 0);
        }
    }

    #pragma unroll
    for (int half = 0; half < 2; ++half) {
        f32x4* acc = half ? accB : accA;
        int rbase = r0 + half * 16;
        #pragma unroll
        for (int i = 0; i < 4; ++i) {
            int rr = rbase + q * 4 + i;
            if (rr < NN) {
                float dv = dinv[rr];
                #pragma unroll
                for (int t = 0; t < NT; ++t)
                    T[(size_t)rr * F + t * 16 + m] = (f16)(acc[t][i] * dv);
            }
        }
    }
}

// ---------------- FUSED: SpMM gather + next-layer GEMM (W from global) ----------------
// 256 threads = 16 rows x 16 lanes; (256,8) -> 8 blocks/CU, VGPR budget 64.
// NO register preloads across the gather (rounds 4 & 6 lesson: any long-lived
// extra state at this budget -> scratch spill, +60-100 MB of traffic). The
// MFMA-phase B-fragment loads hit L1 (16-32 KB shared by all blocks).
// Grid must be exactly NN/16 blocks.
template<int F2>
__global__ __launch_bounds__(256, 8) void spmm_gemm(const f16* __restrict__ T,
                                                    const int* __restrict__ offsets,
                                                    const int* __restrict__ csr_col,
                                                    const float* __restrict__ dinv,
                                                    const float* __restrict__ bias,
                                                    const f16* __restrict__ WtG,
                                                    f16* __restrict__ Tout) {
    constexpr int PITCH = 136;                 // f16 units; 272 B rows, 16B-aligned
    __shared__ f16 hbuf[16 * PITCH];           // 16 rows of h (and out-bounce)
    int tid = threadIdx.x;

    // ---- gather phase ----
    int lane = tid & 15;                       // 16 lanes per row, 16 B each
    int rs   = tid >> 4;                       // 0..15
    int r    = blockIdx.x * 16 + rs;

    const f16x8* Tv = (const f16x8*)T;
    int o0 = offsets[r], o1 = offsets[r + 1];

    float s[8];
    f16x8 self = Tv[(size_t)r * 16 + lane];
    #pragma unroll
    for (int u = 0; u < 8; ++u) s[u] = (float)self[u];

    int j = o0;
    for (; j + 8 <= o1; j += 8) {
        int c0 = csr_col[j],     c1 = csr_col[j + 1], c2 = csr_col[j + 2], c3 = csr_col[j + 3];
        int c4 = csr_col[j + 4], c5 = csr_col[j + 5], c6 = csr_col[j + 6], c7 = csr_col[j + 7];
        f16x8 v0 = Tv[(size_t)c0 * 16 + lane];
        f16x8 v1 = Tv[(size_t)c1 * 16 + lane];
        f16x8 v2 = Tv[(size_t)c2 * 16 + lane];
        f16x8 v3 = Tv[(size_t)c3 * 16 + lane];
        f16x8 v4 = Tv[(size_t)c4 * 16 + lane];
        f16x8 v5 = Tv[(size_t)c5 * 16 + lane];
        f16x8 v6 = Tv[(size_t)c6 * 16 + lane];
        f16x8 v7 = Tv[(size_t)c7 * 16 + lane];
        #pragma unroll
        for (int u = 0; u < 8; ++u) {
            s[u] += ((float)v0[u] + (float)v1[u]) + ((float)v2[u] + (float)v3[u])
                  + ((float)v4[u] + (float)v5[u]) + ((float)v6[u] + (float)v7[u]);
        }
    }
    for (; j + 4 <= o1; j += 4) {
        int c0 = csr_col[j], c1 = csr_col[j + 1], c2 = csr_col[j + 2], c3 = csr_col[j + 3];
        f16x8 v0 = Tv[(size_t)c0 * 16 + lane];
        f16x8 v1 = Tv[(size_t)c1 * 16 + lane];
        f16x8 v2 = Tv[(size_t)c2 * 16 + lane];
        f16x8 v3 = Tv[(size_t)c3 * 16 + lane];
        #pragma unroll
        for (int u = 0; u < 8; ++u)
            s[u] += ((float)v0[u] + (float)v1[u]) + ((float)v2[u] + (float)v3[u]);
    }
    for (; j < o1; ++j) {
        int c = csr_col[j];
        f16x8 v = Tv[(size_t)c * 16 + lane];
        #pragma unroll
        for (int u = 0; u < 8; ++u) s[u] += (float)v[u];
    }

    float dr = dinv[r];
    f16x8 h;
    #pragma unroll
    for (int u = 0; u < 8; ++u) {
        float o = fmaf(dr, s[u], bias[lane * 8 + u]);
        h[u] = (f16)fmaxf(o, 0.f);             // both fused layers have relu
    }
    *(f16x8*)&hbuf[rs * PITCH + lane * 8] = h;
    __syncthreads();                            // h complete

    // ---- MFMA phase: 4 waves; wave fg owns feature group fg of all 16 rows ----
    int wv = tid >> 6, wl = tid & 63;
    int wm = wl & 15, wq = wl >> 4;
    constexpr int FW  = F2 / 4;                 // feats per wave: 32 (F2=128) or 16
    constexpr int NTW = FW / 16;                // tiles per wave: 2 or 1
    int fg = wv;                                // 0..3

    f32x4 acc[NTW];
    #pragma unroll
    for (int t = 0; t < NTW; ++t) acc[t] = (f32x4){0.f, 0.f, 0.f, 0.f};

    #pragma unroll
    for (int c = 0; c < 4; ++c) {
        f16x8 a = *(const f16x8*)&hbuf[wm * PITCH + c * 32 + wq * 8];
        #pragma unroll
        for (int t = 0; t < NTW; ++t) {
            f16x8 b = *(const f16x8*)&WtG[((size_t)(fg * FW + t * 16 + wm)) * 128 + c * 32 + wq * 8];
            acc[t] = __builtin_amdgcn_mfma_f32_16x16x32_f16(a, b, acc[t], 0, 0, 0);
        }
    }
    __syncthreads();                            // all A-reads done before hbuf reuse

    // ---- dinv scale + LDS bounce for coalesced f16 writeout ----
    #pragma unroll
    for (int i = 0; i < 4; ++i) {
        int rloc = wq * 4 + i;
        float dv = dinv[blockIdx.x * 16 + rloc];
        #pragma unroll
        for (int t = 0; t < NTW; ++t)
            hbuf[rloc * PITCH + fg * FW + t * 16 + wm] = (f16)(acc[t][i] * dv);
    }
    __syncthreads();

    constexpr int LPO = F2 / 8;                 // f16x8 per row
    for (int e = tid; e < 16 * LPO; e += 256) {
        int rr = e / LPO, ff = e - rr * LPO;
        ((f16x8*)Tout)[(size_t)(blockIdx.x * 16 + rr) * LPO + ff] =
            *(f16x8*)&hbuf[rr * PITCH + ff * 8];
    }
}

// ---------------- SpMM gather on f16 T (final layer) ----------------
template<int F, bool RELU, bool OUTF16>
__global__ __launch_bounds__(256, 8) void spmm_h(const f16* __restrict__ T,
                                                 const int* __restrict__ offsets,
                                                 const int* __restrict__ csr_col,
                                                 const float* __restrict__ dinv,
                                                 const float* __restrict__ bias,
                                                 void* __restrict__ outv) {
    constexpr int LPR = F / 8;
    constexpr int RPB = 256 / LPR;
    int lane = threadIdx.x % LPR;
    int rs   = threadIdx.x / LPR;
    int r    = blockIdx.x * RPB + rs;
    if (r >= NN) return;

    const f16x8* Tv = (const f16x8*)T;
    int o0 = offsets[r], o1 = offsets[r + 1];

    float s[8];
    f16x8 self = Tv[(size_t)r * LPR + lane];
    #pragma unroll
    for (int u = 0; u < 8; ++u) s[u] = (float)self[u];

    int j = o0;
    for (; j + 8 <= o1; j += 8) {
        int c0 = csr_col[j],     c1 = csr_col[j + 1], c2 = csr_col[j + 2], c3 = csr_col[j + 3];
        int c4 = csr_col[j + 4], c5 = csr_col[j + 5], c6 = csr_col[j + 6], c7 = csr_col[j + 7];
        f16x8 v0 = Tv[(size_t)c0 * LPR + lane];
        f16x8 v1 = Tv[(size_t)c1 * LPR + lane];
        f16x8 v2 = Tv[(size_t)c2 * LPR + lane];
        f16x8 v3 = Tv[(size_t)c3 * LPR + lane];
        f16x8 v4 = Tv[(size_t)c4 * LPR + lane];
        f16x8 v5 = Tv[(size_t)c5 * LPR + lane];
        f16x8 v6 = Tv[(size_t)c6 * LPR + lane];
        f16x8 v7 = Tv[(size_t)c7 * LPR + lane];
        #pragma unroll
        for (int u = 0; u < 8; ++u) {
            s[u] += ((float)v0[u] + (float)v1[u]) + ((float)v2[u] + (float)v3[u])
                  + ((float)v4[u] + (float)v5[u]) + ((float)v6[u] + (float)v7[u]);
        }
    }
    for (; j + 4 <= o1; j += 4) {
        int c0 = csr_col[j], c1 = csr_col[j + 1], c2 = csr_col[j + 2], c3 = csr_col[j + 3];
        f16x8 v0 = Tv[(size_t)c0 * LPR + lane];
        f16x8 v1 = Tv[(size_t)c1 * LPR + lane];
        f16x8 v2 = Tv[(size_t)c2 * LPR + lane];
        f16x8 v3 = Tv[(size_t)c3 * LPR + lane];
        #pragma unroll
        for (int u = 0; u < 8; ++u)
            s[u] += ((float)v0[u] + (float)v1[u]) + ((float)v2[u] + (float)v3[u]);
    }
    for (; j < o1; ++j) {
        int c = csr_col[j];
        f16x8 v = Tv[(size_t)c * LPR + lane];
        #pragma unroll
        for (int u = 0; u < 8; ++u) s[u] += (float)v[u];
    }

    float dr = dinv[r];
    float o[8];
    #pragma unroll
    for (int u = 0; u < 8; ++u) {
        o[u] = fmaf(dr, s[u], bias[lane * 8 + u]);
        if (RELU) o[u] = fmaxf(o[u], 0.f);
    }

    if (OUTF16) {
        f16x8 h;
        #pragma unroll
        for (int u = 0; u < 8; ++u) h[u] = (f16)o[u];
        ((f16x8*)outv)[(size_t)r * LPR + lane] = h;
    } else {
        float* outF = (float*)outv;
        float4 lo = make_float4(o[0], o[1], o[2], o[3]);
        float4 hi = make_float4(o[4], o[5], o[6], o[7]);
        *(float4*)&outF[(size_t)r * F + lane * 8]     = lo;
        *(float4*)&outF[(size_t)r * F + lane * 8 + 4] = hi;
    }
}

// ---------------- launch ----------------

extern "C" void kernel_launch(void* const* d_in, const int* in_sizes, int n_in,
                              void* d_out, int out_size, void* d_ws, size_t ws_size,
                              hipStream_t stream) {
    const float* x  = (const float*)d_in[0];
    const int*   ei = (const int*)d_in[1];
    const float* W0 = (const float*)d_in[2];
    const float* b0 = (const float*)d_in[3];
    const float* W1 = (const float*)d_in[4];
    const float* b1 = (const float*)d_in[5];
    const float* W2 = (const float*)d_in[6];
    const float* b2 = (const float*)d_in[7];
    float* out = (float*)d_out;

    const int* row = ei;
    const int* col = ei + NE;

    char* wsp = (char*)d_ws;
    auto alloc = [&](size_t bytes) {
        char* p = wsp;
        wsp += (bytes + 255) & ~(size_t)255;
        return p;
    };
    int*   bcursor = (int*)alloc((size_t)BK2 * 4);          // run cursor, ends as bucket count
    int2*  binned  = (int2*)alloc((size_t)BK2 * CAP2 * 8);  // 15.2 MB
    int*   offsets = (int*)alloc((size_t)(NN + 1) * 4);
    float* dinv    = (float*)alloc((size_t)NN * 4);
    int*   csr_col = (int*)alloc((size_t)NE * 4);
    f16*   Tbuf    = (f16*)alloc((size_t)NN * 128 * 2);
    f16*   Hbuf    = (f16*)alloc((size_t)NN * 128 * 2);
    f16*   Wt1     = (f16*)alloc((size_t)128 * 128 * 2);    // W1 transposed f16
    f16*   Wt2     = (f16*)alloc((size_t)64 * 128 * 2);     // W2 transposed f16

    // prep (zero bcursor + W transposes) + adjacency build
    prep<<<96, 256, 0, stream>>>(W1, W2, Wt1, Wt2, bcursor);
    bin_edges<<<(NE + CHUNK2 - 1) / CHUNK2, 256, 0, stream>>>(row, col, bcursor, binned);
    build_csr<<<BK2, 256, 0, stream>>>(bcursor, binned, offsets, dinv, csr_col);

    const int GB128 = (NN + 127) / 128;  // 782
    const int FB16  = NN / 16;           // 6250, exact (NN % 16 == 0)

    // layer 1 GEMM (fp32 x): T1 = f16(dinv * (x @ W0))
    gemm_mfma128<<<GB128, 256, 0, stream>>>(x, W0, dinv, Tbuf);
    // fused: H1 = relu(spmm(T1) + b0);  T2 = f16(dinv * (H1 @ W1))
    spmm_gemm<128><<<FB16, 256, 0, stream>>>(Tbuf, offsets, csr_col, dinv, b0, Wt1, Hbuf);
    // fused: H2 = relu(spmm(T2) + b1);  T3 = f16(dinv * (H2 @ W2))
    spmm_gemm<64><<<FB16, 256, 0, stream>>>(Hbuf, offsets, csr_col, dinv, b1, Wt2, Tbuf);
    // final: out = spmm(T3) + b2   (fp32, no relu)
    spmm_h<64, false, false><<<(NN + 31) / 32, 256, 0, stream>>>(Tbuf, offsets, csr_col, dinv, b2, out);
}